// Round 8
// baseline (186.157 us; speedup 1.0000x reference)
//
#include <hip/hip_runtime.h>

#define B 8
#define C 64
#define H 128
#define W 128
#define HW (H * W)
#define OC 27
#define KK 9
#define COUT 64
#define KDIM 576           // 9*64
#define LDSROW 1152        // bytes per pixel row (576 * 2B)
#define NPIX 16            // pixels per k_main workgroup
#define NPAIR (NPIX * KK)  // 144

typedef __attribute__((ext_vector_type(8))) short s16x8;
typedef __attribute__((ext_vector_type(4))) float f32x4;

__device__ inline ushort f2bf(float f) {
    union { float f; unsigned u; } uv;
    uv.f = f;
    unsigned r = uv.u + 0x7FFF + ((uv.u >> 16) & 1);
    return (ushort)(r >> 16);
}
__device__ inline float bf2f(ushort u) {
    return __uint_as_float((unsigned)u << 16);
}

// async global->LDS: per-lane global src, wave-uniform LDS dest (+lane*4)
__device__ inline void async_dword(const void* gsrc, void* ldst) {
    __builtin_amdgcn_global_load_lds(
        (const __attribute__((address_space(1))) unsigned*)gsrc,
        (__attribute__((address_space(3))) unsigned*)ldst, 4, 0, 0);
}

// ---------------------------------------------------------------------------
// Kernel 1: transpose x (NCHW fp32) -> xTb (NHWC bf16).
// ---------------------------------------------------------------------------
__global__ __launch_bounds__(256) void k_transpose_x(const float* __restrict__ x,
                                                     ushort* __restrict__ xTb) {
    __shared__ float lds[64][65];
    int b = blockIdx.x >> 8;
    int tile = blockIdx.x & 255;
    int hw0 = tile * 64;
    int lane = threadIdx.x & 63;
    int cg = threadIdx.x >> 6;
#pragma unroll
    for (int r = 0; r < 16; ++r) {
        int c = cg * 16 + r;
        lds[c][lane] = x[(size_t)(b * C + c) * HW + hw0 + lane];
    }
    __syncthreads();
#pragma unroll
    for (int r = 0; r < 16; ++r) {
        int hwl = cg * 16 + r;
        xTb[(size_t)(b * HW + hw0 + hwl) * C + lane] = f2bf(lds[lane][hwl]);
    }
}

// ---------------------------------------------------------------------------
// Kernel 2: repack w (Cout,C,3,3) fp32 -> wB[o][K] bf16, K = tap*64 + c.
// ---------------------------------------------------------------------------
__global__ __launch_bounds__(256) void k_prep_w(const float* __restrict__ w,
                                                ushort* __restrict__ wB) {
    int idx = blockIdx.x * 256 + threadIdx.x;
    if (idx >= COUT * KDIM) return;
    int o = idx / KDIM;
    int Kx = idx % KDIM;
    int k = Kx >> 6;
    int c = Kx & 63;
    wB[idx] = f2bf(w[(size_t)(o * C + c) * KK + k]);
}

// ---------------------------------------------------------------------------
// Kernel 2b: repack ow (27,C,3,3) fp32 -> awB[32][576] bf16 (rows 27..31 = 0).
// ---------------------------------------------------------------------------
__global__ __launch_bounds__(256) void k_prep_aw(const float* __restrict__ ow,
                                                 ushort* __restrict__ awB) {
    int idx = blockIdx.x * 256 + threadIdx.x;  // o*576 + K
    if (idx >= 32 * KDIM) return;
    int o = idx / KDIM;
    int Kx = idx % KDIM;
    int tap = Kx >> 6;
    int c = Kx & 63;
    float v = (o < OC) ? ow[((size_t)o * C + c) * KK + tap] : 0.0f;
    awB[idx] = f2bf(v);
}

// ---------------------------------------------------------------------------
// Kernel 3: offset/mask conv as im2col GEMM (unchanged).
// ---------------------------------------------------------------------------
__global__ __launch_bounds__(256) void k_om(const ushort* __restrict__ xTb,
                                            const ushort* __restrict__ awB,
                                            const float* __restrict__ ob,
                                            float* __restrict__ om) {
    __shared__ __align__(16) char xwin[3 * 66 * 128];  // 25344 B
    int tid = threadIdx.x;
    int lane = tid & 63;
    int wv = tid >> 6;
    int blk = blockIdx.x;  // b*256 + h*2 + (w0/64)
    int b = blk >> 8;
    int h = (blk >> 1) & 127;
    int w0 = (blk & 1) * 64;

    const ushort* xb = xTb + (size_t)b * (HW * C);
    int ch2 = tid & 31;
#pragma unroll
    for (int it = 0; it < 25; ++it) {
        int pi = it * 8 + (tid >> 5);
        if (pi < 198) {
            int row = pi / 66;
            int col = pi - row * 66;
            int y = h - 1 + row;
            int xc = w0 - 1 + col;
            unsigned v = 0;
            if ((unsigned)y < H && (unsigned)xc < W)
                v = *(const unsigned*)(xb + ((size_t)(y * W + xc) << 6) + ch2 * 2);
            int byte = (pi * 128 + ch2 * 4) ^ ((col & 7) << 4);
            *(unsigned*)(xwin + byte) = v;
        }
    }
    __syncthreads();

    f32x4 acc0 = {0.f, 0.f, 0.f, 0.f};
    f32x4 acc1 = {0.f, 0.f, 0.f, 0.f};
    int pixl = lane & 15;
    int q = lane >> 4;
    int base_col = wv * 16 + pixl;
    const ushort* a0 = awB + (size_t)pixl * KDIM + q * 8;
    const ushort* a1 = awB + (size_t)(16 + pixl) * KDIM + q * 8;
#pragma unroll
    for (int s = 0; s < 18; ++s) {
        int tap = s >> 1;
        int row = tap / 3;
        int cs = tap - row * 3;
        int col = base_col + cs;
        int c0b = ((s & 1) * 32 + q * 8) * 2;
        int byte = (((row * 66 + col) << 7) + c0b) ^ ((col & 7) << 4);
        s16x8 bfrag = *(const s16x8*)(xwin + byte);
        s16x8 af0 = *(const s16x8*)(a0 + s * 32);
        s16x8 af1 = *(const s16x8*)(a1 + s * 32);
        acc0 = __builtin_amdgcn_mfma_f32_16x16x32_bf16(af0, bfrag, acc0, 0, 0, 0);
        acc1 = __builtin_amdgcn_mfma_f32_16x16x32_bf16(af1, bfrag, acc1, 0, 0, 0);
    }

    int pix = wv * 16 + pixl;
#pragma unroll
    for (int j = 0; j < 4; ++j) {
        int oc = q * 4 + j;
        om[(((size_t)b * OC + oc) * H + h) * W + w0 + pix] = acc0[j] + ob[oc];
        int oc1 = 16 + q * 4 + j;
        if (oc1 < OC)
            om[(((size_t)b * OC + oc1) * H + h) * W + w0 + pix] = acc1[j] + ob[oc1];
    }
}

// ---------------------------------------------------------------------------
// Kernel 4: fused deformable sampling + MFMA einsum.
//  A0: per (pixel,tap): 2 row-base offsets + 4 slot weights (mask folded).
//  A1: per pixel: issue 18 fire-and-forget global_load_lds (wave-uniform
//      row base + lane*4, zero VGPRs held) -> raw[wv]; vmcnt(0); blend:
//      lane=channel, 4 ds_read_u16 + 4 FMA + pack + ds_write_b16 into samp.
//  B : 18 x mfma_f32_16x16x32_bf16 per wave.
// ---------------------------------------------------------------------------
__global__ __launch_bounds__(256, 4) void k_main(const ushort* __restrict__ xTb,
                                                 const float* __restrict__ om,
                                                 const ushort* __restrict__ wB,
                                                 const float* __restrict__ bias,
                                                 float* __restrict__ out) {
    __shared__ __align__(16) char smem[NPIX * LDSROW];  // 18432 B
    __shared__ __align__(16) ushort raw[4][KK][2][128]; // 18432 B
    __shared__ float4 meta_w[NPAIR];                    // 2304 B
    __shared__ int2 meta_o[NPAIR];                      // 1152 B

    int tid = threadIdx.x;
    int lane = tid & 63;
    int wv = tid >> 6;
    int pb = blockIdx.x * NPIX;
    int b = pb >> 14;
    int rem = pb & (HW - 1);
    int h = rem >> 7;
    int w0 = rem & (W - 1);

    // ---- Phase A0: per-(pixel,tap) slot metadata ----
    if (tid < NPAIR) {
        int k = tid >> 4;
        int p = tid & 15;
        int dh = k / 3 - 1;
        int dw = k % 3 - 1;
        const float* o0 = om + ((size_t)b * OC) * HW + h * W + w0 + p;
        float offx = o0[(size_t)k * HW];
        float offy = o0[(size_t)(KK + k) * HW];
        float mlog = o0[(size_t)(2 * KK + k) * HW];
        float mask = 1.0f / (1.0f + __expf(-mlog));
        float gx = (float)(w0 + p + dw) + offx;
        float gy = (float)(h + dh) + offy;
        float x0f = floorf(gx), y0f = floorf(gy);
        int x0 = (int)x0f, y0 = (int)y0f;
        int x1 = x0 + 1, y1 = y0 + 1;
        float wx1 = gx - x0f, wy1 = gy - y0f;
        float wx0 = 1.0f - wx1, wy0 = 1.0f - wy1;
        float rw0 = ((unsigned)y0 < H) ? wy0 * mask : 0.0f;
        float rw1 = ((unsigned)y1 < H) ? wy1 * mask : 0.0f;
        int y0c = min(max(y0, 0), H - 1), y1c = min(max(y1, 0), H - 1);
        int colbase = min(max(x0, 0), W - 2);
        float cw0 = 0.0f, cw1 = 0.0f;
        if ((unsigned)x0 < W) { if (x0 == colbase) cw0 += wx0; else cw1 += wx0; }
        if ((unsigned)x1 < W) { if (x1 == colbase) cw0 += wx1; else cw1 += wx1; }
        // (row0*slot0, row0*slot1, row1*slot0, row1*slot1)
        meta_w[tid] = make_float4(rw0 * cw0, rw0 * cw1, rw1 * cw0, rw1 * cw1);
        meta_o[tid] = make_int2((y0c * W + colbase) * (C * 2),
                                (y1c * W + colbase) * (C * 2));
    }
    __syncthreads();

    // ---- Phase A1: async row staging + blend ----
    const char* xbase = (const char*)(xTb + (size_t)b * (HW * C));
#pragma unroll 1
    for (int pp = 0; pp < 4; ++pp) {
        int p = wv * 4 + pp;
        __builtin_amdgcn_sched_barrier(0);  // keep DMA issue after prev blend
#pragma unroll
        for (int k = 0; k < KK; ++k) {
            int2 mo = meta_o[k * 16 + p];
            async_dword(xbase + mo.x + lane * 4, &raw[wv][k][0][0]);
            async_dword(xbase + mo.y + lane * 4, &raw[wv][k][1][0]);
        }
        asm volatile("s_waitcnt vmcnt(0)" ::: "memory");
        __builtin_amdgcn_sched_barrier(0);  // no ds_read hoist above wait
        int vlds = p * LDSROW + ((lane * 2) ^ ((p & 7) << 4));
#pragma unroll
        for (int k = 0; k < KK; ++k) {
            float4 mw = meta_w[k * 16 + p];
            float r00 = bf2f(raw[wv][k][0][lane]);
            float r01 = bf2f(raw[wv][k][0][64 + lane]);
            float r10 = bf2f(raw[wv][k][1][lane]);
            float r11 = bf2f(raw[wv][k][1][64 + lane]);
            float v = r00 * mw.x + r01 * mw.y + r10 * mw.z + r11 * mw.w;
            *(ushort*)(smem + vlds + k * 128) = f2bf(v);
        }
    }
    __syncthreads();

    // ---- Phase B: MFMA ----
    f32x4 acc;
#pragma unroll
    for (int j = 0; j < 4; ++j) acc[j] = bias[wv * 16 + (lane >> 4) * 4 + j];

    int pix = lane & 15;
    const ushort* wrow = wB + (size_t)(wv * 16 + pix) * KDIM + (lane >> 4) * 8;
#pragma unroll
    for (int s = 0; s < 18; ++s) {
        int kbyte = s * 64 + (lane >> 4) * 16;
        int byte = (pix * LDSROW + kbyte) ^ ((pix & 7) << 4);
        s16x8 bfrag = *(const s16x8*)(smem + byte);
        s16x8 afrag = *(const s16x8*)(wrow + s * 32);
        acc = __builtin_amdgcn_mfma_f32_16x16x32_bf16(afrag, bfrag, acc, 0, 0, 0);
    }

    float* obase = out + ((size_t)(b * COUT + wv * 16 + (lane >> 4) * 4) * HW) + h * W + w0;
#pragma unroll
    for (int j = 0; j < 4; ++j) obase[(size_t)j * HW + pix] = acc[j];
}

// ---------------------------------------------------------------------------
extern "C" void kernel_launch(void* const* d_in, const int* in_sizes, int n_in,
                              void* d_out, int out_size, void* d_ws, size_t ws_size,
                              hipStream_t stream) {
    const float* x = (const float*)d_in[0];
    const float* ow = (const float*)d_in[1];
    const float* ob = (const float*)d_in[2];
    const float* w = (const float*)d_in[3];
    const float* bias = (const float*)d_in[4];
    float* out = (float*)d_out;

    float* om = (float*)d_ws;                           // B*27*HW = 3538944 f
    ushort* xTb = (ushort*)(om + (size_t)B * OC * HW);  // B*HW*C ushort
    ushort* wB = xTb + (size_t)B * HW * C;              // 36864 ushort
    ushort* awB = wB + (size_t)COUT * KDIM;             // 18432 ushort
    // total ~31.1 MB

    hipLaunchKernelGGL(k_transpose_x, dim3(B * 256), dim3(256), 0, stream, x, xTb);
    hipLaunchKernelGGL(k_prep_w, dim3((COUT * KDIM + 255) / 256), dim3(256), 0,
                       stream, w, wB);
    hipLaunchKernelGGL(k_prep_aw, dim3((32 * KDIM + 255) / 256), dim3(256), 0,
                       stream, ow, awB);
    hipLaunchKernelGGL(k_om, dim3(B * H * 2), dim3(256), 0, stream, xTb, awB, ob, om);
    hipLaunchKernelGGL(k_main, dim3(B * HW / NPIX), dim3(256), 0, stream,
                       xTb, om, wB, bias, out);
}

// Round 9
// 162.771 us; speedup vs baseline: 1.1437x; 1.1437x over previous
//
#include <hip/hip_runtime.h>

#define B 8
#define C 64
#define H 128
#define W 128
#define HW (H * W)
#define OC 27
#define KK 9
#define COUT 64
#define KDIM 576           // 9*64
#define LDSROW 1152        // bytes per pixel row (576 * 2B)
#define NPIX 16            // pixels per k_main workgroup
#define NPAIR (NPIX * KK)  // 144

typedef __attribute__((ext_vector_type(8))) short s16x8;
typedef __attribute__((ext_vector_type(4))) float f32x4;

__device__ inline ushort f2bf(float f) {
    union { float f; unsigned u; } uv;
    uv.f = f;
    unsigned r = uv.u + 0x7FFF + ((uv.u >> 16) & 1);
    return (ushort)(r >> 16);
}
__device__ inline float bf2f(ushort u) {
    return __uint_as_float((unsigned)u << 16);
}

// ---------------------------------------------------------------------------
// Kernel 1: transpose x (NCHW fp32) -> xTb (NHWC bf16). XCD-chunked swizzle.
// ---------------------------------------------------------------------------
__global__ __launch_bounds__(256) void k_transpose_x(const float* __restrict__ x,
                                                     ushort* __restrict__ xTb) {
    __shared__ float lds[64][65];
    int j = blockIdx.x;
    int vb = (j & 7) * 256 + (j >> 3);  // batch b -> XCD b
    int b = vb >> 8;
    int tile = vb & 255;
    int hw0 = tile * 64;
    int lane = threadIdx.x & 63;
    int cg = threadIdx.x >> 6;
#pragma unroll
    for (int r = 0; r < 16; ++r) {
        int c = cg * 16 + r;
        lds[c][lane] = x[(size_t)(b * C + c) * HW + hw0 + lane];
    }
    __syncthreads();
#pragma unroll
    for (int r = 0; r < 16; ++r) {
        int hwl = cg * 16 + r;
        xTb[(size_t)(b * HW + hw0 + hwl) * C + lane] = f2bf(lds[lane][hwl]);
    }
}

// ---------------------------------------------------------------------------
// Kernel 2: repack w (Cout,C,3,3) fp32 -> wB[o][K] bf16, K = tap*64 + c.
// ---------------------------------------------------------------------------
__global__ __launch_bounds__(256) void k_prep_w(const float* __restrict__ w,
                                                ushort* __restrict__ wB) {
    int idx = blockIdx.x * 256 + threadIdx.x;
    if (idx >= COUT * KDIM) return;
    int o = idx / KDIM;
    int Kx = idx % KDIM;
    int k = Kx >> 6;
    int c = Kx & 63;
    wB[idx] = f2bf(w[(size_t)(o * C + c) * KK + k]);
}

// ---------------------------------------------------------------------------
// Kernel 2b: repack ow (27,C,3,3) fp32 -> awB[32][576] bf16 (rows 27..31 = 0).
// ---------------------------------------------------------------------------
__global__ __launch_bounds__(256) void k_prep_aw(const float* __restrict__ ow,
                                                 ushort* __restrict__ awB) {
    int idx = blockIdx.x * 256 + threadIdx.x;  // o*576 + K
    if (idx >= 32 * KDIM) return;
    int o = idx / KDIM;
    int Kx = idx % KDIM;
    int tap = Kx >> 6;
    int c = Kx & 63;
    float v = (o < OC) ? ow[((size_t)o * C + c) * KK + tap] : 0.0f;
    awB[idx] = f2bf(v);
}

// ---------------------------------------------------------------------------
// Kernel 3: offset/mask conv (im2col MFMA GEMM) + FUSED meta production.
// After the GEMM, om values are transposed via LDS ([64][29], conflict-free)
// and each (pixel,tap)'s sampling metadata (4 mask-premultiplied bilinear
// slot-weights + 2 clamped row-base byte offsets) is computed here and
// written pixel-major to global. No om tensor, no A0 phase in k_main.
// ---------------------------------------------------------------------------
__global__ __launch_bounds__(256) void k_om(const ushort* __restrict__ xTb,
                                            const ushort* __restrict__ awB,
                                            const float* __restrict__ ob,
                                            float4* __restrict__ gW,
                                            int2* __restrict__ gO) {
    __shared__ __align__(16) char xwin[3 * 66 * 128];  // 25344 B
    int tid = threadIdx.x;
    int lane = tid & 63;
    int wv = tid >> 6;
    int j = blockIdx.x;
    int vb = (j & 7) * 256 + (j >> 3);  // batch b -> XCD b
    int b = vb >> 8;
    int h = (vb >> 1) & 127;
    int w0 = (vb & 1) * 64;

    // ---- stage 3x66x64ch bf16, zero-filled at borders ----
    const ushort* xb = xTb + (size_t)b * (HW * C);
    int ch2 = tid & 31;
#pragma unroll
    for (int it = 0; it < 25; ++it) {
        int pi = it * 8 + (tid >> 5);
        if (pi < 198) {
            int row = pi / 66;
            int col = pi - row * 66;
            int y = h - 1 + row;
            int xc = w0 - 1 + col;
            unsigned v = 0;
            if ((unsigned)y < H && (unsigned)xc < W)
                v = *(const unsigned*)(xb + ((size_t)(y * W + xc) << 6) + ch2 * 2);
            int byte = (pi * 128 + ch2 * 4) ^ ((col & 7) << 4);
            *(unsigned*)(xwin + byte) = v;
        }
    }
    __syncthreads();

    f32x4 acc0 = {0.f, 0.f, 0.f, 0.f};
    f32x4 acc1 = {0.f, 0.f, 0.f, 0.f};
    int pixl = lane & 15;
    int q = lane >> 4;
    int base_col = wv * 16 + pixl;
    const ushort* a0 = awB + (size_t)pixl * KDIM + q * 8;
    const ushort* a1 = awB + (size_t)(16 + pixl) * KDIM + q * 8;
#pragma unroll
    for (int s = 0; s < 18; ++s) {
        int tap = s >> 1;
        int row = tap / 3;
        int cs = tap - row * 3;
        int col = base_col + cs;
        int c0b = ((s & 1) * 32 + q * 8) * 2;
        int byte = (((row * 66 + col) << 7) + c0b) ^ ((col & 7) << 4);
        s16x8 bfrag = *(const s16x8*)(xwin + byte);
        s16x8 af0 = *(const s16x8*)(a0 + s * 32);
        s16x8 af1 = *(const s16x8*)(a1 + s * 32);
        acc0 = __builtin_amdgcn_mfma_f32_16x16x32_bf16(af0, bfrag, acc0, 0, 0, 0);
        acc1 = __builtin_amdgcn_mfma_f32_16x16x32_bf16(af1, bfrag, acc1, 0, 0, 0);
    }

    // ---- transpose om to LDS (reuse xwin): omt[64 pix][29] ----
    __syncthreads();  // all xwin reads done before overwrite
    float* omt = (float*)xwin;
    {
        int pix = wv * 16 + pixl;
#pragma unroll
        for (int jj = 0; jj < 4; ++jj) {
            int oc = q * 4 + jj;
            omt[pix * 29 + oc] = acc0[jj] + ob[oc];
        }
#pragma unroll
        for (int jj = 0; jj < 4; ++jj) {
            int oc1 = 16 + q * 4 + jj;
            if (oc1 < OC) omt[pix * 29 + oc1] = acc1[jj] + ob[oc1];
        }
    }
    __syncthreads();

    // ---- meta for 576 (pixel,tap) pairs ----
    size_t base9 = ((size_t)b * HW + h * W + w0) * KK;
    for (int t = tid; t < 64 * KK; t += 256) {
        int pix = t / 9;
        int k = t - pix * 9;
        float offx = omt[pix * 29 + k];
        float offy = omt[pix * 29 + 9 + k];
        float mlog = omt[pix * 29 + 18 + k];
        int dh = k / 3 - 1;
        int dw = k % 3 - 1;
        float mask = 1.0f / (1.0f + __expf(-mlog));
        float gx = (float)(w0 + pix + dw) + offx;
        float gy = (float)(h + dh) + offy;
        float x0f = floorf(gx), y0f = floorf(gy);
        int x0 = (int)x0f, y0 = (int)y0f;
        int x1 = x0 + 1, y1 = y0 + 1;
        float wx1 = gx - x0f, wy1 = gy - y0f;
        float wx0 = 1.0f - wx1, wy0 = 1.0f - wy1;
        float rw0 = ((unsigned)y0 < H) ? wy0 * mask : 0.0f;
        float rw1 = ((unsigned)y1 < H) ? wy1 * mask : 0.0f;
        int y0c = min(max(y0, 0), H - 1), y1c = min(max(y1, 0), H - 1);
        int colbase = min(max(x0, 0), W - 2);
        float cw0 = 0.0f, cw1 = 0.0f;
        if ((unsigned)x0 < W) { if (x0 == colbase) cw0 += wx0; else cw1 += wx0; }
        if ((unsigned)x1 < W) { if (x1 == colbase) cw0 += wx1; else cw1 += wx1; }
        gW[base9 + t] = make_float4(rw0 * cw0, rw0 * cw1, rw1 * cw0, rw1 * cw1);
        gO[base9 + t] = make_int2((y0c * W + colbase) * (C * 2),
                                  (y1c * W + colbase) * (C * 2));
    }
}

// ---------------------------------------------------------------------------
// Kernel 4: fused deformable sampling + MFMA einsum.
//  A : 2 coalesced cooperative loads pull all 144 pairs' meta into LDS.
//  A1: per pixel: 9 meta reads -> 18 addresses -> 18 batched full-wave
//      global_load_dword (row = 256B contiguous; lanes<32 slot0, >=32 slot1)
//      -> sched_barrier -> blend (shfl_xor(32) combine, cvt_pk, half-wave
//      ds_write_b32 into swizzled samp).
//  B : 18 x mfma_f32_16x16x32_bf16 per wave.
// ---------------------------------------------------------------------------
__global__ __launch_bounds__(256, 5) void k_main(const ushort* __restrict__ xTb,
                                                 const float4* __restrict__ gW,
                                                 const int2* __restrict__ gO,
                                                 const ushort* __restrict__ wB,
                                                 const float* __restrict__ bias,
                                                 float* __restrict__ out) {
    __shared__ __align__(16) char smem[NPIX * LDSROW];  // 18432 B
    __shared__ float4 mw_lds[NPAIR];                    // 2304 B
    __shared__ int2 mo_lds[NPAIR];                      // 1152 B

    int tid = threadIdx.x;
    int lane = tid & 63;
    int wv = tid >> 6;
    int jb = blockIdx.x;
    int vb = (jb & 7) * 1024 + (jb >> 3);  // batch b -> XCD b
    int pb = vb * NPIX;
    int b = pb >> 14;
    int rem = pb & (HW - 1);
    int h = rem >> 7;
    int w0 = rem & (W - 1);

    // ---- Phase A: cooperative meta load (pixel-major, coalesced) ----
    size_t base9 = ((size_t)b * HW + rem) * KK;
    if (tid < NPAIR) mw_lds[tid] = gW[base9 + tid];
    if (tid < NPAIR) mo_lds[tid] = gO[base9 + tid];
    __syncthreads();

    // ---- Phase A1: batched full-wave row gathers ----
    const char* xbase = (const char*)(xTb + (size_t)b * (HW * C));
    bool lo_half = lane < 32;
#pragma unroll 1
    for (int pp = 0; pp < 4; ++pp) {
        int p = wv * 4 + pp;
        float4 mwv[KK];
        int2 mov[KK];
#pragma unroll
        for (int k = 0; k < KK; ++k) {
            mwv[k] = mw_lds[p * 9 + k];
            mov[k] = mo_lds[p * 9 + k];
        }
        unsigned d0[KK], d1[KK];
#pragma unroll
        for (int k = 0; k < KK; ++k) {
            d0[k] = *(const unsigned*)(xbase + mov[k].x + lane * 4);
            d1[k] = *(const unsigned*)(xbase + mov[k].y + lane * 4);
        }
        __builtin_amdgcn_sched_barrier(0);  // all 18 loads issued before blends
        int vlds = p * LDSROW + (((lane & 31) * 4) ^ ((p & 7) << 4));
#pragma unroll
        for (int k = 0; k < KK; ++k) {
            float wa = lo_half ? mwv[k].x : mwv[k].y;  // row0, my slot
            float wb_ = lo_half ? mwv[k].z : mwv[k].w; // row1, my slot
            float a0 = __uint_as_float(d0[k] << 16);
            float a1 = __uint_as_float(d0[k] & 0xFFFF0000u);
            float b0 = __uint_as_float(d1[k] << 16);
            float b1 = __uint_as_float(d1[k] & 0xFFFF0000u);
            float p0 = a0 * wa + b0 * wb_;
            float p1 = a1 * wa + b1 * wb_;
            float q0 = __shfl_xor(p0, 32, 64);
            float q1 = __shfl_xor(p1, 32, 64);
            float s0 = p0 + q0, s1 = p1 + q1;
            unsigned pk;
            asm("v_cvt_pk_bf16_f32 %0, %1, %2" : "=v"(pk) : "v"(s0), "v"(s1));
            if (lane < 32) *(unsigned*)(smem + vlds + k * 128) = pk;
        }
    }
    __syncthreads();

    // ---- Phase B: MFMA ----
    f32x4 acc;
#pragma unroll
    for (int j = 0; j < 4; ++j) acc[j] = bias[wv * 16 + (lane >> 4) * 4 + j];

    int pix = lane & 15;
    const ushort* wrow = wB + (size_t)(wv * 16 + pix) * KDIM + (lane >> 4) * 8;
#pragma unroll
    for (int s = 0; s < 18; ++s) {
        int kbyte = s * 64 + (lane >> 4) * 16;
        int byte = (pix * LDSROW + kbyte) ^ ((pix & 7) << 4);
        s16x8 bfrag = *(const s16x8*)(smem + byte);
        s16x8 afrag = *(const s16x8*)(wrow + s * 32);
        acc = __builtin_amdgcn_mfma_f32_16x16x32_bf16(afrag, bfrag, acc, 0, 0, 0);
    }

    float* obase = out + ((size_t)(b * COUT + wv * 16 + (lane >> 4) * 4) * HW) + h * W + w0;
#pragma unroll
    for (int j = 0; j < 4; ++j) obase[(size_t)j * HW + pix] = acc[j];
}

// ---------------------------------------------------------------------------
extern "C" void kernel_launch(void* const* d_in, const int* in_sizes, int n_in,
                              void* d_out, int out_size, void* d_ws, size_t ws_size,
                              hipStream_t stream) {
    const float* x = (const float*)d_in[0];
    const float* ow = (const float*)d_in[1];
    const float* ob = (const float*)d_in[2];
    const float* w = (const float*)d_in[3];
    const float* bias = (const float*)d_in[4];
    float* out = (float*)d_out;

    float4* gW = (float4*)d_ws;                         // B*HW*9 float4 = 18.9 MB
    int2* gO = (int2*)(gW + (size_t)B * HW * KK);       // B*HW*9 int2   =  9.4 MB
    ushort* xTb = (ushort*)(gO + (size_t)B * HW * KK);  // B*HW*C ushort = 16.8 MB
    ushort* wB = xTb + (size_t)B * HW * C;              // 36864 ushort
    ushort* awB = wB + (size_t)COUT * KDIM;             // 18432 ushort
    // total ~45.2 MB

    hipLaunchKernelGGL(k_transpose_x, dim3(B * 256), dim3(256), 0, stream, x, xTb);
    hipLaunchKernelGGL(k_prep_w, dim3((COUT * KDIM + 255) / 256), dim3(256), 0,
                       stream, w, wB);
    hipLaunchKernelGGL(k_prep_aw, dim3((32 * KDIM + 255) / 256), dim3(256), 0,
                       stream, ow, awB);
    hipLaunchKernelGGL(k_om, dim3(B * H * 2), dim3(256), 0, stream, xTb, awB, ob, gW, gO);
    hipLaunchKernelGGL(k_main, dim3(B * HW / NPIX), dim3(256), 0, stream,
                       xTb, gW, gO, wB, bias, out);
}